// Round 5
// baseline (226.997 us; speedup 1.0000x reference)
//
#include <hip/hip_runtime.h>
#include <hip/hip_bf16.h>

#define N_NODES 50000
#define KK 32
#define EE 128
#define NK (N_NODES * KK)
#define NE (N_NODES * EE)
#define WAVES 4
#define PR 32   // rows per GEMM block

typedef __hip_bfloat16 bf16;
typedef unsigned int u32;
typedef unsigned short u16;
typedef __attribute__((ext_vector_type(8))) short bf16x8;
typedef __attribute__((ext_vector_type(4))) float f32x4;
typedef __attribute__((ext_vector_type(2))) float f32x2;

__device__ __forceinline__ float bflo(u32 u) { return __uint_as_float(u << 16); }
__device__ __forceinline__ float bfhi(u32 u) { return __uint_as_float(u & 0xFFFF0000u); }
__device__ __forceinline__ u16 f2bu(float x) {
    union { bf16 b; u16 u; } c; c.b = __float2bfloat16(x); return c.u;
}
__device__ __forceinline__ u32 packbf2(float lo, float hi) {
    return (u32)f2bu(lo) | ((u32)f2bu(hi) << 16);
}

// ---------------------------------------------------------------------------
// Merged prep+pack: blocks 0..255 compute A=WhL@Wf / B=WhR@Wf elements and
// write Wghp frag layout DIRECTLY; blocks 256..319 pack Wstp from Ws.
// grid 320, block 128.
// ---------------------------------------------------------------------------
__global__ void prep_pack(const float* __restrict__ Wh, const float* __restrict__ Wf,
                          const float* __restrict__ bfv, const float* __restrict__ bh,
                          const float* __restrict__ Ws,
                          u16* __restrict__ Wghp, u16* __restrict__ Wstp,
                          float* agf, float* bh2f) {
    int bx = blockIdx.x;
    int tid = threadIdx.x;
    if (bx < 256) {
        int m = bx >> 7;
        int r = bx & 127;
        int c = tid;
        const float* whrow = Wh + (long)r * (2 * EE) + m * EE;
        float acc = 0.f;
        for (int j = 0; j < EE; ++j)
            acc += whrow[j] * Wf[(long)j * EE + c];
        // frag coords: K-index k=c, N-index j=m*128+r
        int jt = (m * EE + r) >> 4, col = r & 15;
        int t = c >> 5, quad = (c >> 3) & 3, jj = c & 7;
        Wghp[((long)(t * 16 + jt)) * 512 + (quad * 16 + col) * 8 + jj] = f2bu(acc);
        if (c == 0) {
            float accb = 0.f;
            for (int j = 0; j < EE; ++j) accb += whrow[j] * bfv[j];
            if (m) bh2f[r] = accb + bh[r];
            else   agf[r] = accb;
        }
    } else {
        int bb = bx - 256, t = bb >> 3, jt = bb & 7;
        for (int f = tid; f < 512; f += 128) {
            int lane = f >> 3, jj = f & 7;
            int col = lane & 15, quad = lane >> 4;
            int r = jt * 16 + col;
            int c = t * 32 + quad * 8 + jj;
            Wstp[(long)bb * 512 + f] = f2bu(Ws[(long)r * (2 * EE) + c]);
        }
    }
}

// ---------------------------------------------------------------------------
// Distance MLP: d(x) = sum_e W2[e]*relu(W1[e]*x + b1[e]) + b2.
// d written f32 into the out_position region of d_out.
// ---------------------------------------------------------------------------
__global__ __launch_bounds__(256) void dist_mlp(const float* __restrict__ dists,
                                                const float* __restrict__ W1,
                                                const float* __restrict__ b1,
                                                const float* __restrict__ W2,
                                                const float* __restrict__ b2v,
                                                float* __restrict__ dst) {
    __shared__ float4 w4[EE];
    int tid = threadIdx.x;
    if (tid < EE) w4[tid] = make_float4(W1[tid], b1[tid], W2[tid], 0.f);
    __syncthreads();
    float b2s = b2v[0];
    int i0 = (blockIdx.x * 256 + tid) * 4;
    float x[4], acc[4];
    #pragma unroll
    for (int j = 0; j < 4; ++j) {
        int i = i0 + j;
        x[j] = (i < NK) ? dists[i] : 0.f;
        acc[j] = b2s;
    }
    for (int e = 0; e < EE; ++e) {
        float4 w = w4[e];
        #pragma unroll
        for (int j = 0; j < 4; ++j)
            acc[j] += w.z * fmaxf(w.x * x[j] + w.y, 0.f);
    }
    #pragma unroll
    for (int j = 0; j < 4; ++j) {
        int i = i0 + j;
        if (i < NK) dst[i] = acc[j];
    }
}

// ---------------------------------------------------------------------------
// MFMA GEMM: [g|h2] = feature @ [A;B]^T + bias  -> bf16 into out_structure
// region. Block: 32 rows x 256 cols, 4 waves x (2 m-tiles x 4 j-tiles).
// Feature staged bf16 in LDS, row stride 68 u32 (2-way bank alias = free).
// grid ceil(N/32), block 256.
// ---------------------------------------------------------------------------
__global__ __launch_bounds__(256) void proj_gh_mfma(const float* __restrict__ feature,
                                                    const u16* __restrict__ Wghp,
                                                    const float* __restrict__ agf,
                                                    const float* __restrict__ bh2f,
                                                    u16* __restrict__ g,
                                                    u16* __restrict__ h2) {
    __shared__ u32 ft[PR * 68];
    int tid = threadIdx.x;
    int n0 = blockIdx.x * PR;
    for (int idx = tid; idx < PR * 32; idx += 256) {   // float4 units, 32/row
        int rr = idx >> 5, c4 = idx & 31;
        long row = n0 + rr; if (row >= N_NODES) row = N_NODES - 1;
        float4 v = ((const float4*)(feature + row * EE))[c4];
        ft[rr * 68 + 2 * c4]     = packbf2(v.x, v.y);
        ft[rr * 68 + 2 * c4 + 1] = packbf2(v.z, v.w);
    }
    __syncthreads();
    int lane = tid & 63, wave = tid >> 6;
    int col = lane & 15, quad = lane >> 4;
    f32x4 acc[2][4] = {};
    #pragma unroll
    for (int t = 0; t < 4; ++t) {
        bf16x8 a0 = *(const bf16x8*)&ft[col * 68 + t * 16 + quad * 4];
        bf16x8 a1 = *(const bf16x8*)&ft[(16 + col) * 68 + t * 16 + quad * 4];
        #pragma unroll
        for (int jt = 0; jt < 4; ++jt) {
            int jtg = wave * 4 + jt;
            bf16x8 b = *(const bf16x8*)&Wghp[((long)(t * 16 + jtg) * 64 + lane) * 8];
            acc[0][jt] = __builtin_amdgcn_mfma_f32_16x16x32_bf16(a0, b, acc[0][jt], 0, 0, 0);
            acc[1][jt] = __builtin_amdgcn_mfma_f32_16x16x32_bf16(a1, b, acc[1][jt], 0, 0, 0);
        }
    }
    #pragma unroll
    for (int jt = 0; jt < 4; ++jt) {
        int j = wave * 64 + jt * 16 + col;             // 0..255
        float bias = (j < EE) ? agf[j] : bh2f[j - EE];
        u16* dst = (j < EE) ? (g + j) : (h2 + (j - EE));
        #pragma unroll
        for (int mt = 0; mt < 2; ++mt)
            #pragma unroll
            for (int i = 0; i < 4; ++i) {
                long row = n0 + mt * 16 + quad * 4 + i;
                if (row < N_NODES) dst[row * EE] = f2bu(acc[mt][jt][i] + bias);
            }
    }
}

// ---------------------------------------------------------------------------
// Fused gather + relu + Wp-dot + mean (R11 = R8 structure + packed f32 math).
// Wave-uniform n -> argmax row scalarizes (s_load), readfirstlane(row) ->
// SALU gather address + saddr global_load_dword. The (even,odd) j-pair per
// lane is a natural <2 x float>: fma and mean-add issue as v_pk_fma_f32 /
// v_pk_add_f32 (2 elems per 2-cyc issue slot). fma/max semantics identical
// to fmaf/fmaxf -> bit-identical results. grid N/4, block 256.
// ---------------------------------------------------------------------------
__global__ __launch_bounds__(256) void fused_msg(const int* __restrict__ argmax,
                                                 const u32* __restrict__ g,
                                                 const u32* __restrict__ h2,
                                                 const float* __restrict__ Wp,
                                                 const float* __restrict__ bpv,
                                                 float* outpos,
                                                 u32* __restrict__ meanws) {
    __shared__ u32 tile[WAVES][KK / 2][65];
    int tid = threadIdx.x;
    int lane = tid & 63;
    int wave = __builtin_amdgcn_readfirstlane(tid >> 6);
    int n = blockIdx.x * WAVES + wave;                 // wave-uniform

    const int* arow = argmax + (long)n * KK;           // uniform -> SMEM loads
    const float* drow = outpos + (long)n * KK;         // uniform base -> saddr

    u32 hu = h2[(long)n * (EE / 2) + lane];
    f32x2 hv; hv[0] = bflo(hu); hv[1] = bfhi(hu);
    float2 wpv = ((const float2*)Wp)[lane];
    float bpf = bpv[0];

    f32x2 am = {0.f, 0.f};
    const f32x2 zero2 = {0.f, 0.f};
    float ppe = 0.f;
    #pragma unroll
    for (int k = 0; k < KK; ++k) {
        int row = __builtin_amdgcn_readfirstlane(arow[k]);  // scalar row
        float dk = drow[k];                                  // lane-uniform
        const u32* gp = g + (long)row * (EE / 2);            // SALU address
        u32 gu = gp[lane];                                   // saddr + v_lane4
        f32x2 gv; gv[0] = bflo(gu); gv[1] = bfhi(gu);
        f32x2 dk2 = {dk, dk};
        f32x2 m = __builtin_elementwise_max(
                      __builtin_elementwise_fma(dk2, gv, hv), zero2);
        am += m;                                             // v_pk_add_f32
        float p = fmaf(m[1], wpv.y, m[0] * wpv.x);
        if (k & 1) tile[wave][k >> 1][lane] = packbf2(ppe, p);
        else       ppe = p;
    }
    meanws[(long)n * (EE / 2) + lane] = packbf2(am[0] * (1.f / KK), am[1] * (1.f / KK));

    int d = lane & 15;
    int j0 = (lane >> 4) * 16;
    f32x2 s = {0.f, 0.f};
    #pragma unroll
    for (int i = 0; i < 16; ++i) {
        u32 v = tile[wave][d][j0 + i];
        f32x2 pv; pv[0] = bflo(v); pv[1] = bfhi(v);
        s += pv;                                             // v_pk_add_f32
    }
    float s0 = s[0], s1 = s[1];
    s0 += __shfl_xor(s0, 16);
    s1 += __shfl_xor(s1, 16);
    s0 += __shfl_xor(s0, 32);
    s1 += __shfl_xor(s1, 32);
    if (lane < 16) {
        float2 o = make_float2(s0 + bpf, s1 + bpf);
        *(float2*)&outpos[(long)n * KK + 2 * d] = o;
    }
}

// ---------------------------------------------------------------------------
// MFMA GEMM: out_structure = [mean | ea] @ Ws^T + bs -> f32, overwrites the
// out_structure region. Block: 32 rows x 128 cols, K=256 (8 k-steps),
// 4 waves x (2 m-tiles x 2 j-tiles). A staged bf16 in LDS, stride 132 u32.
// grid ceil(N/32), block 256.
// ---------------------------------------------------------------------------
__global__ __launch_bounds__(256) void out_struct_mfma(const u16* __restrict__ meanws,
                                                       const float* __restrict__ edge_attr,
                                                       const u16* __restrict__ Wstp,
                                                       const float* __restrict__ bs,
                                                       float* __restrict__ outs) {
    __shared__ u32 at[PR * 132];
    int tid = threadIdx.x;
    int n0 = blockIdx.x * PR;
    for (int idx = tid; idx < PR * 64; idx += 256) {   // mean: u32 units, 64/row
        int rr = idx >> 6, c = idx & 63;
        long row = n0 + rr; if (row >= N_NODES) row = N_NODES - 1;
        at[rr * 132 + c] = ((const u32*)meanws)[row * 64 + c];
    }
    for (int idx = tid; idx < PR * 32; idx += 256) {   // ea: float4 units, 32/row
        int rr = idx >> 5, c4 = idx & 31;
        long row = n0 + rr; if (row >= N_NODES) row = N_NODES - 1;
        float4 v = ((const float4*)(edge_attr + row * EE))[c4];
        at[rr * 132 + 64 + 2 * c4]     = packbf2(v.x, v.y);
        at[rr * 132 + 64 + 2 * c4 + 1] = packbf2(v.z, v.w);
    }
    __syncthreads();
    int lane = tid & 63, wave = tid >> 6;
    int col = lane & 15, quad = lane >> 4;
    f32x4 acc[2][2] = {};
    #pragma unroll
    for (int t = 0; t < 8; ++t) {
        bf16x8 a0 = *(const bf16x8*)&at[col * 132 + t * 16 + quad * 4];
        bf16x8 a1 = *(const bf16x8*)&at[(16 + col) * 132 + t * 16 + quad * 4];
        #pragma unroll
        for (int jt = 0; jt < 2; ++jt) {
            int jtg = wave * 2 + jt;
            bf16x8 b = *(const bf16x8*)&Wstp[((long)(t * 8 + jtg) * 64 + lane) * 8];
            acc[0][jt] = __builtin_amdgcn_mfma_f32_16x16x32_bf16(a0, b, acc[0][jt], 0, 0, 0);
            acc[1][jt] = __builtin_amdgcn_mfma_f32_16x16x32_bf16(a1, b, acc[1][jt], 0, 0, 0);
        }
    }
    #pragma unroll
    for (int jt = 0; jt < 2; ++jt) {
        int j = wave * 32 + jt * 16 + col;             // 0..127
        float bias = bs[j];
        #pragma unroll
        for (int mt = 0; mt < 2; ++mt)
            #pragma unroll
            for (int i = 0; i < 4; ++i) {
                long row = n0 + mt * 16 + quad * 4 + i;
                if (row < N_NODES) outs[row * EE + j] = acc[mt][jt][i] + bias;
            }
    }
}

extern "C" void kernel_launch(void* const* d_in, const int* in_sizes, int n_in,
                              void* d_out, int out_size, void* d_ws, size_t ws_size,
                              hipStream_t stream) {
    const float* feature   = (const float*)d_in[0];
    const float* dists_max = (const float*)d_in[1];
    const int* dists_argmax = (const int*)d_in[2];
    const float* edge_attr = (const float*)d_in[3];
    const float* W1 = (const float*)d_in[4];
    const float* b1 = (const float*)d_in[5];
    const float* W2 = (const float*)d_in[6];
    const float* b2 = (const float*)d_in[7];
    const float* Wf = (const float*)d_in[8];
    const float* bf = (const float*)d_in[9];
    const float* Wh = (const float*)d_in[10];
    const float* bh = (const float*)d_in[11];
    const float* Wp = (const float*)d_in[12];
    const float* bp = (const float*)d_in[13];
    const float* Ws = (const float*)d_in[14];
    const float* bs = (const float*)d_in[15];

    float* outpos = (float*)d_out;        // [N,K] f32: d scratch, then pos
    float* outs   = outpos + NK;          // [N,E] f32: g+h2 bf16 scratch, then out_structure
    u16* g  = (u16*)outs;                 // [N,E] bf16  (12.8 MB)
    u16* h2 = g + NE;                     // [N,E] bf16  (12.8 MB)

    // Workspace (same footprint as R5-R10): 0.26 MB f32 + 12.8 MB bf16.
    float* Acm  = (float*)d_ws;           // [EE*EE]  (unused, layout anchor)
    float* Bcm  = Acm + EE * EE;          // [EE*EE]  (unused)
    float* agf  = Bcm + EE * EE;          // [EE]
    float* bh2f = agf + EE;               // [EE]
    float* Wst  = bh2f + EE;              // [2*EE*EE] area, reused for packs:
    u16* Wghp = (u16*)Wst;                //   64 KB (4*16 frag-tiles)
    u16* Wstp = Wghp + 64 * 512;          //   64 KB (8*8 frag-tiles)
    u16* meanws = (u16*)(Wst + 2 * EE * EE);  // [N*E] bf16 (unchanged offset)

    int gemm_blocks = (N_NODES + PR - 1) / PR;
    prep_pack<<<320, 128, 0, stream>>>(Wh, Wf, bf, bh, Ws, Wghp, Wstp, agf, bh2f);
    dist_mlp<<<(NK + 1023) / 1024, 256, 0, stream>>>(dists_max, W1, b1, W2, b2, outpos);
    proj_gh_mfma<<<gemm_blocks, 256, 0, stream>>>(feature, Wghp, agf, bh2f, g, h2);
    fused_msg<<<N_NODES / WAVES, 256, 0, stream>>>(dists_argmax, (const u32*)g,
                                                   (const u32*)h2, Wp, bp,
                                                   outpos, (u32*)meanws);
    out_struct_mfma<<<gemm_blocks, 256, 0, stream>>>(meanws, edge_attr, Wstp, bs, outs);
}

// Round 6
// 215.523 us; speedup vs baseline: 1.0532x; 1.0532x over previous
//
#include <hip/hip_runtime.h>
#include <hip/hip_bf16.h>

#define N_NODES 50000
#define KK 32
#define EE 128
#define NK (N_NODES * KK)
#define NE (N_NODES * EE)
#define WAVES 4
#define PR 32   // rows per GEMM block
#define GEMM_BLOCKS ((N_NODES + PR - 1) / PR)   // 1563
#define DIST_BLOCKS ((NK + 1023) / 1024)        // 1563

typedef __hip_bfloat16 bf16;
typedef unsigned int u32;
typedef unsigned short u16;
typedef __attribute__((ext_vector_type(8))) short bf16x8;
typedef __attribute__((ext_vector_type(4))) float f32x4;
typedef __attribute__((ext_vector_type(2))) float f32x2;

__device__ __forceinline__ float bflo(u32 u) { return __uint_as_float(u << 16); }
__device__ __forceinline__ float bfhi(u32 u) { return __uint_as_float(u & 0xFFFF0000u); }
__device__ __forceinline__ u16 f2bu(float x) {
    union { bf16 b; u16 u; } c; c.b = __float2bfloat16(x); return c.u;
}
__device__ __forceinline__ u32 packbf2(float lo, float hi) {
    return (u32)f2bu(lo) | ((u32)f2bu(hi) << 16);
}

// ---------------------------------------------------------------------------
// Merged prep+pack: blocks 0..255 compute A=WhL@Wf / B=WhR@Wf elements and
// write Wghp frag layout DIRECTLY; blocks 256..319 pack Wstp from Ws.
// grid 320, block 128.
// ---------------------------------------------------------------------------
__global__ void prep_pack(const float* __restrict__ Wh, const float* __restrict__ Wf,
                          const float* __restrict__ bfv, const float* __restrict__ bh,
                          const float* __restrict__ Ws,
                          u16* __restrict__ Wghp, u16* __restrict__ Wstp,
                          float* agf, float* bh2f) {
    int bx = blockIdx.x;
    int tid = threadIdx.x;
    if (bx < 256) {
        int m = bx >> 7;
        int r = bx & 127;
        int c = tid;
        const float* whrow = Wh + (long)r * (2 * EE) + m * EE;
        float acc = 0.f;
        for (int j = 0; j < EE; ++j)
            acc += whrow[j] * Wf[(long)j * EE + c];
        // frag coords: K-index k=c, N-index j=m*128+r
        int jt = (m * EE + r) >> 4, col = r & 15;
        int t = c >> 5, quad = (c >> 3) & 3, jj = c & 7;
        Wghp[((long)(t * 16 + jt)) * 512 + (quad * 16 + col) * 8 + jj] = f2bu(acc);
        if (c == 0) {
            float accb = 0.f;
            for (int j = 0; j < EE; ++j) accb += whrow[j] * bfv[j];
            if (m) bh2f[r] = accb + bh[r];
            else   agf[r] = accb;
        }
    } else {
        int bb = bx - 256, t = bb >> 3, jt = bb & 7;
        for (int f = tid; f < 512; f += 128) {
            int lane = f >> 3, jj = f & 7;
            int col = lane & 15, quad = lane >> 4;
            int r = jt * 16 + col;
            int c = t * 32 + quad * 8 + jj;
            Wstp[(long)bb * 512 + f] = f2bu(Ws[(long)r * (2 * EE) + c]);
        }
    }
}

// ---------------------------------------------------------------------------
// Role-split launch (R12): blocks [0, GEMM_BLOCKS) run the proj_gh MFMA GEMM;
// blocks [GEMM_BLOCKS, GEMM_BLOCKS+DIST_BLOCKS) run the distance MLP. The two
// are independent; merging removes a launch gap and overlaps dist's VALU
// work with proj's memory stalls. LDS is shared (dist uses a 2KB alias).
// grid GEMM_BLOCKS+DIST_BLOCKS, block 256.
// ---------------------------------------------------------------------------
__global__ __launch_bounds__(256) void proj_dist(const float* __restrict__ feature,
                                                 const u16* __restrict__ Wghp,
                                                 const float* __restrict__ agf,
                                                 const float* __restrict__ bh2f,
                                                 u16* __restrict__ g,
                                                 u16* __restrict__ h2,
                                                 const float* __restrict__ dists,
                                                 const float* __restrict__ W1,
                                                 const float* __restrict__ b1,
                                                 const float* __restrict__ W2,
                                                 const float* __restrict__ b2v,
                                                 float* __restrict__ dstd) {
    __shared__ u32 ft[PR * 68];
    int tid = threadIdx.x;
    int bx = blockIdx.x;
    if (bx < GEMM_BLOCKS) {
        // ---- proj_gh role: [g|h2] = feature @ [A;B]^T + bias -> bf16 ----
        int n0 = bx * PR;
        for (int idx = tid; idx < PR * 32; idx += 256) {   // float4 units
            int rr = idx >> 5, c4 = idx & 31;
            long row = n0 + rr; if (row >= N_NODES) row = N_NODES - 1;
            float4 v = ((const float4*)(feature + row * EE))[c4];
            ft[rr * 68 + 2 * c4]     = packbf2(v.x, v.y);
            ft[rr * 68 + 2 * c4 + 1] = packbf2(v.z, v.w);
        }
        __syncthreads();
        int lane = tid & 63, wave = tid >> 6;
        int col = lane & 15, quad = lane >> 4;
        f32x4 acc[2][4] = {};
        #pragma unroll
        for (int t = 0; t < 4; ++t) {
            bf16x8 a0 = *(const bf16x8*)&ft[col * 68 + t * 16 + quad * 4];
            bf16x8 a1 = *(const bf16x8*)&ft[(16 + col) * 68 + t * 16 + quad * 4];
            #pragma unroll
            for (int jt = 0; jt < 4; ++jt) {
                int jtg = wave * 4 + jt;
                bf16x8 b = *(const bf16x8*)&Wghp[((long)(t * 16 + jtg) * 64 + lane) * 8];
                acc[0][jt] = __builtin_amdgcn_mfma_f32_16x16x32_bf16(a0, b, acc[0][jt], 0, 0, 0);
                acc[1][jt] = __builtin_amdgcn_mfma_f32_16x16x32_bf16(a1, b, acc[1][jt], 0, 0, 0);
            }
        }
        #pragma unroll
        for (int jt = 0; jt < 4; ++jt) {
            int j = wave * 64 + jt * 16 + col;             // 0..255
            float bias = (j < EE) ? agf[j] : bh2f[j - EE];
            u16* dst = (j < EE) ? (g + j) : (h2 + (j - EE));
            #pragma unroll
            for (int mt = 0; mt < 2; ++mt)
                #pragma unroll
                for (int i = 0; i < 4; ++i) {
                    long row = n0 + mt * 16 + quad * 4 + i;
                    if (row < N_NODES) dst[row * EE] = f2bu(acc[mt][jt][i] + bias);
                }
        }
    } else {
        // ---- dist_mlp role: d(x) = sum_e W2[e]*relu(W1[e]*x+b1[e]) + b2 ----
        float4* w4 = (float4*)ft;                          // 2KB alias
        if (tid < EE) w4[tid] = make_float4(W1[tid], b1[tid], W2[tid], 0.f);
        __syncthreads();
        float b2s = b2v[0];
        int i0 = ((bx - GEMM_BLOCKS) * 256 + tid) * 4;
        float x[4], acc[4];
        #pragma unroll
        for (int j = 0; j < 4; ++j) {
            int i = i0 + j;
            x[j] = (i < NK) ? dists[i] : 0.f;
            acc[j] = b2s;
        }
        for (int e = 0; e < EE; ++e) {
            float4 w = w4[e];
            #pragma unroll
            for (int j = 0; j < 4; ++j)
                acc[j] += w.z * fmaxf(w.x * x[j] + w.y, 0.f);
        }
        #pragma unroll
        for (int j = 0; j < 4; ++j) {
            int i = i0 + j;
            if (i < NK) dstd[i] = acc[j];
        }
    }
}

// ---------------------------------------------------------------------------
// Fused gather + relu + Wp-dot + mean (R12 = R11 + explicit 8-deep gather
// ring). Wave-uniform n -> argmax row scalarizes; 8 gather loads in flight
// per wave (gbuf ring, fully static indexing) to cover L2-miss latency.
// Packed f32 math (v_pk_fma/v_pk_add) kept from R11; bit-identical results.
// grid N/4, block 256.
// ---------------------------------------------------------------------------
__global__ __launch_bounds__(256) void fused_msg(const int* __restrict__ argmax,
                                                 const u32* __restrict__ g,
                                                 const u32* __restrict__ h2,
                                                 const float* __restrict__ Wp,
                                                 const float* __restrict__ bpv,
                                                 float* outpos,
                                                 u32* __restrict__ meanws) {
    __shared__ u32 tile[WAVES][KK / 2][65];
    int tid = threadIdx.x;
    int lane = tid & 63;
    int wave = __builtin_amdgcn_readfirstlane(tid >> 6);
    int n = blockIdx.x * WAVES + wave;                 // wave-uniform

    const int* arow = argmax + (long)n * KK;           // uniform -> SMEM loads
    const float* drow = outpos + (long)n * KK;         // uniform base -> saddr

    u32 hu = h2[(long)n * (EE / 2) + lane];
    f32x2 hv; hv[0] = bflo(hu); hv[1] = bfhi(hu);
    float2 wpv = ((const float2*)Wp)[lane];
    float bpf = bpv[0];

    // scalar row indices (SGPRs)
    int rows[KK];
    #pragma unroll
    for (int k = 0; k < KK; ++k)
        rows[k] = __builtin_amdgcn_readfirstlane(arow[k]);

    // 8-deep gather ring: 8 loads in flight per wave
    u32 gbuf[8];
    #pragma unroll
    for (int i = 0; i < 8; ++i)
        gbuf[i] = g[(long)rows[i] * (EE / 2) + lane];

    f32x2 am = {0.f, 0.f};
    const f32x2 zero2 = {0.f, 0.f};
    float ppe = 0.f;
    #pragma unroll
    for (int k = 0; k < KK; ++k) {
        u32 gu = gbuf[k & 7];
        if (k + 8 < KK)
            gbuf[k & 7] = g[(long)rows[k + 8] * (EE / 2) + lane];
        float dk = drow[k];                                  // lane-uniform
        f32x2 gv; gv[0] = bflo(gu); gv[1] = bfhi(gu);
        f32x2 dk2 = {dk, dk};
        f32x2 m = __builtin_elementwise_max(
                      __builtin_elementwise_fma(dk2, gv, hv), zero2);
        am += m;                                             // v_pk_add_f32
        float p = fmaf(m[1], wpv.y, m[0] * wpv.x);
        if (k & 1) tile[wave][k >> 1][lane] = packbf2(ppe, p);
        else       ppe = p;
    }
    meanws[(long)n * (EE / 2) + lane] = packbf2(am[0] * (1.f / KK), am[1] * (1.f / KK));

    int d = lane & 15;
    int j0 = (lane >> 4) * 16;
    f32x2 s = {0.f, 0.f};
    #pragma unroll
    for (int i = 0; i < 16; ++i) {
        u32 v = tile[wave][d][j0 + i];
        f32x2 pv; pv[0] = bflo(v); pv[1] = bfhi(v);
        s += pv;                                             // v_pk_add_f32
    }
    float s0 = s[0], s1 = s[1];
    s0 += __shfl_xor(s0, 16);
    s1 += __shfl_xor(s1, 16);
    s0 += __shfl_xor(s0, 32);
    s1 += __shfl_xor(s1, 32);
    if (lane < 16) {
        float2 o = make_float2(s0 + bpf, s1 + bpf);
        *(float2*)&outpos[(long)n * KK + 2 * d] = o;
    }
}

// ---------------------------------------------------------------------------
// MFMA GEMM: out_structure = [mean | ea] @ Ws^T + bs -> f32, overwrites the
// out_structure region. Block: 32 rows x 128 cols, K=256 (8 k-steps),
// 4 waves x (2 m-tiles x 2 j-tiles). A staged bf16 in LDS, stride 132 u32.
// grid ceil(N/32), block 256.
// ---------------------------------------------------------------------------
__global__ __launch_bounds__(256) void out_struct_mfma(const u16* __restrict__ meanws,
                                                       const float* __restrict__ edge_attr,
                                                       const u16* __restrict__ Wstp,
                                                       const float* __restrict__ bs,
                                                       float* __restrict__ outs) {
    __shared__ u32 at[PR * 132];
    int tid = threadIdx.x;
    int n0 = blockIdx.x * PR;
    for (int idx = tid; idx < PR * 64; idx += 256) {   // mean: u32 units, 64/row
        int rr = idx >> 6, c = idx & 63;
        long row = n0 + rr; if (row >= N_NODES) row = N_NODES - 1;
        at[rr * 132 + c] = ((const u32*)meanws)[row * 64 + c];
    }
    for (int idx = tid; idx < PR * 32; idx += 256) {   // ea: float4 units, 32/row
        int rr = idx >> 5, c4 = idx & 31;
        long row = n0 + rr; if (row >= N_NODES) row = N_NODES - 1;
        float4 v = ((const float4*)(edge_attr + row * EE))[c4];
        at[rr * 132 + 64 + 2 * c4]     = packbf2(v.x, v.y);
        at[rr * 132 + 64 + 2 * c4 + 1] = packbf2(v.z, v.w);
    }
    __syncthreads();
    int lane = tid & 63, wave = tid >> 6;
    int col = lane & 15, quad = lane >> 4;
    f32x4 acc[2][2] = {};
    #pragma unroll
    for (int t = 0; t < 8; ++t) {
        bf16x8 a0 = *(const bf16x8*)&at[col * 132 + t * 16 + quad * 4];
        bf16x8 a1 = *(const bf16x8*)&at[(16 + col) * 132 + t * 16 + quad * 4];
        #pragma unroll
        for (int jt = 0; jt < 2; ++jt) {
            int jtg = wave * 2 + jt;
            bf16x8 b = *(const bf16x8*)&Wstp[((long)(t * 8 + jtg) * 64 + lane) * 8];
            acc[0][jt] = __builtin_amdgcn_mfma_f32_16x16x32_bf16(a0, b, acc[0][jt], 0, 0, 0);
            acc[1][jt] = __builtin_amdgcn_mfma_f32_16x16x32_bf16(a1, b, acc[1][jt], 0, 0, 0);
        }
    }
    #pragma unroll
    for (int jt = 0; jt < 2; ++jt) {
        int j = wave * 32 + jt * 16 + col;             // 0..127
        float bias = bs[j];
        #pragma unroll
        for (int mt = 0; mt < 2; ++mt)
            #pragma unroll
            for (int i = 0; i < 4; ++i) {
                long row = n0 + mt * 16 + quad * 4 + i;
                if (row < N_NODES) outs[row * EE + j] = acc[mt][jt][i] + bias;
            }
    }
}

extern "C" void kernel_launch(void* const* d_in, const int* in_sizes, int n_in,
                              void* d_out, int out_size, void* d_ws, size_t ws_size,
                              hipStream_t stream) {
    const float* feature   = (const float*)d_in[0];
    const float* dists_max = (const float*)d_in[1];
    const int* dists_argmax = (const int*)d_in[2];
    const float* edge_attr = (const float*)d_in[3];
    const float* W1 = (const float*)d_in[4];
    const float* b1 = (const float*)d_in[5];
    const float* W2 = (const float*)d_in[6];
    const float* b2 = (const float*)d_in[7];
    const float* Wf = (const float*)d_in[8];
    const float* bf = (const float*)d_in[9];
    const float* Wh = (const float*)d_in[10];
    const float* bh = (const float*)d_in[11];
    const float* Wp = (const float*)d_in[12];
    const float* bp = (const float*)d_in[13];
    const float* Ws = (const float*)d_in[14];
    const float* bs = (const float*)d_in[15];

    float* outpos = (float*)d_out;        // [N,K] f32: d scratch, then pos
    float* outs   = outpos + NK;          // [N,E] f32: g+h2 bf16 scratch, then out_structure
    u16* g  = (u16*)outs;                 // [N,E] bf16  (12.8 MB)
    u16* h2 = g + NE;                     // [N,E] bf16  (12.8 MB)

    // Workspace (same footprint as R5-R11): 0.26 MB f32 + 12.8 MB bf16.
    float* Acm  = (float*)d_ws;           // [EE*EE]  (unused, layout anchor)
    float* Bcm  = Acm + EE * EE;          // [EE*EE]  (unused)
    float* agf  = Bcm + EE * EE;          // [EE]
    float* bh2f = agf + EE;               // [EE]
    float* Wst  = bh2f + EE;              // [2*EE*EE] area, reused for packs:
    u16* Wghp = (u16*)Wst;                //   64 KB (4*16 frag-tiles)
    u16* Wstp = Wghp + 64 * 512;          //   64 KB (8*8 frag-tiles)
    u16* meanws = (u16*)(Wst + 2 * EE * EE);  // [N*E] bf16 (unchanged offset)

    prep_pack<<<320, 128, 0, stream>>>(Wh, Wf, bf, bh, Ws, Wghp, Wstp, agf, bh2f);
    proj_dist<<<GEMM_BLOCKS + DIST_BLOCKS, 256, 0, stream>>>(
        feature, Wghp, agf, bh2f, g, h2,
        dists_max, W1, b1, W2, b2, outpos);
    fused_msg<<<N_NODES / WAVES, 256, 0, stream>>>(dists_argmax, (const u32*)g,
                                                   (const u32*)h2, Wp, bp,
                                                   outpos, (u32*)meanws);
    out_struct_mfma<<<GEMM_BLOCKS, 256, 0, stream>>>(meanws, edge_attr, Wstp, bs, outs);
}

// Round 7
// 210.094 us; speedup vs baseline: 1.0805x; 1.0258x over previous
//
#include <hip/hip_runtime.h>
#include <hip/hip_bf16.h>

#define N_NODES 50000
#define KK 32
#define EE 128
#define NK (N_NODES * KK)
#define NE (N_NODES * EE)
#define WAVES 4
#define PR 32   // rows per GEMM block
#define GEMM_BLOCKS ((N_NODES + PR - 1) / PR)   // 1563
#define DIST_BLOCKS ((NK + 1023) / 1024)        // 1563

typedef __hip_bfloat16 bf16;
typedef unsigned int u32;
typedef unsigned short u16;
typedef __attribute__((ext_vector_type(8))) short bf16x8;
typedef __attribute__((ext_vector_type(4))) float f32x4;
typedef __attribute__((ext_vector_type(2))) float f32x2;

__device__ __forceinline__ float bflo(u32 u) { return __uint_as_float(u << 16); }
__device__ __forceinline__ float bfhi(u32 u) { return __uint_as_float(u & 0xFFFF0000u); }
__device__ __forceinline__ u16 f2bu(float x) {
    union { bf16 b; u16 u; } c; c.b = __float2bfloat16(x); return c.u;
}
__device__ __forceinline__ u32 packbf2(float lo, float hi) {
    return (u32)f2bu(lo) | ((u32)f2bu(hi) << 16);
}

// ---------------------------------------------------------------------------
// Merged prep+pack: blocks 0..255 compute A=WhL@Wf / B=WhR@Wf elements and
// write Wghp frag layout DIRECTLY; blocks 256..319 pack Wstp from Ws.
// grid 320, block 128.
// ---------------------------------------------------------------------------
__global__ void prep_pack(const float* __restrict__ Wh, const float* __restrict__ Wf,
                          const float* __restrict__ bfv, const float* __restrict__ bh,
                          const float* __restrict__ Ws,
                          u16* __restrict__ Wghp, u16* __restrict__ Wstp,
                          float* agf, float* bh2f) {
    int bx = blockIdx.x;
    int tid = threadIdx.x;
    if (bx < 256) {
        int m = bx >> 7;
        int r = bx & 127;
        int c = tid;
        const float* whrow = Wh + (long)r * (2 * EE) + m * EE;
        float acc = 0.f;
        for (int j = 0; j < EE; ++j)
            acc += whrow[j] * Wf[(long)j * EE + c];
        // frag coords: K-index k=c, N-index j=m*128+r
        int jt = (m * EE + r) >> 4, col = r & 15;
        int t = c >> 5, quad = (c >> 3) & 3, jj = c & 7;
        Wghp[((long)(t * 16 + jt)) * 512 + (quad * 16 + col) * 8 + jj] = f2bu(acc);
        if (c == 0) {
            float accb = 0.f;
            for (int j = 0; j < EE; ++j) accb += whrow[j] * bfv[j];
            if (m) bh2f[r] = accb + bh[r];
            else   agf[r] = accb;
        }
    } else {
        int bb = bx - 256, t = bb >> 3, jt = bb & 7;
        for (int f = tid; f < 512; f += 128) {
            int lane = f >> 3, jj = f & 7;
            int col = lane & 15, quad = lane >> 4;
            int r = jt * 16 + col;
            int c = t * 32 + quad * 8 + jj;
            Wstp[(long)bb * 512 + f] = f2bu(Ws[(long)r * (2 * EE) + c]);
        }
    }
}

// ---------------------------------------------------------------------------
// Role-split launch: blocks [0, GEMM_BLOCKS) run the proj_gh MFMA GEMM;
// blocks [GEMM_BLOCKS, +DIST_BLOCKS) run the distance MLP.
// R13: GEMM epilogue routes accumulators through LDS so g/h2 stores become
// full 256B-contiguous dwordx4 (4 stores/thread) instead of 64 scalar u16
// stores/thread at stride 256B (4x32B partial-line segments per instr).
// Bit-identical values. grid GEMM_BLOCKS+DIST_BLOCKS, block 256.
// ---------------------------------------------------------------------------
__global__ __launch_bounds__(256) void proj_dist(const float* __restrict__ feature,
                                                 const u16* __restrict__ Wghp,
                                                 const float* __restrict__ agf,
                                                 const float* __restrict__ bh2f,
                                                 u16* __restrict__ g,
                                                 u16* __restrict__ h2,
                                                 const float* __restrict__ dists,
                                                 const float* __restrict__ W1,
                                                 const float* __restrict__ b1,
                                                 const float* __restrict__ W2,
                                                 const float* __restrict__ b2v,
                                                 float* __restrict__ dstd) {
    __shared__ u32 shb[PR * 132];                      // 16.9KB: ft alias + ct alias
    int tid = threadIdx.x;
    int bx = blockIdx.x;
    if (bx < GEMM_BLOCKS) {
        // ---- proj_gh role: [g|h2] = feature @ [A;B]^T + bias -> bf16 ----
        u32* ft = shb;                                 // [PR][68] u32 staging
        int n0 = bx * PR;
        for (int idx = tid; idx < PR * 32; idx += 256) {   // float4 units
            int rr = idx >> 5, c4 = idx & 31;
            long row = n0 + rr; if (row >= N_NODES) row = N_NODES - 1;
            float4 v = ((const float4*)(feature + row * EE))[c4];
            ft[rr * 68 + 2 * c4]     = packbf2(v.x, v.y);
            ft[rr * 68 + 2 * c4 + 1] = packbf2(v.z, v.w);
        }
        __syncthreads();
        int lane = tid & 63, wave = tid >> 6;
        int col = lane & 15, quad = lane >> 4;
        f32x4 acc[2][4] = {};
        #pragma unroll
        for (int t = 0; t < 4; ++t) {
            bf16x8 a0 = *(const bf16x8*)&ft[col * 68 + t * 16 + quad * 4];
            bf16x8 a1 = *(const bf16x8*)&ft[(16 + col) * 68 + t * 16 + quad * 4];
            #pragma unroll
            for (int jt = 0; jt < 4; ++jt) {
                int jtg = wave * 4 + jt;
                bf16x8 b = *(const bf16x8*)&Wghp[((long)(t * 16 + jtg) * 64 + lane) * 8];
                acc[0][jt] = __builtin_amdgcn_mfma_f32_16x16x32_bf16(a0, b, acc[0][jt], 0, 0, 0);
                acc[1][jt] = __builtin_amdgcn_mfma_f32_16x16x32_bf16(a1, b, acc[1][jt], 0, 0, 0);
            }
        }
        __syncthreads();                               // all ft reads done
        // phase 1: bias + bf16-pack into LDS tile ct[32][264] u16
        u16* ct = (u16*)shb;
        #pragma unroll
        for (int jt = 0; jt < 4; ++jt) {
            int j = wave * 64 + jt * 16 + col;         // 0..255
            float bias = (j < EE) ? agf[j] : bh2f[j - EE];
            #pragma unroll
            for (int mt = 0; mt < 2; ++mt)
                #pragma unroll
                for (int i = 0; i < 4; ++i) {
                    int rr = mt * 16 + quad * 4 + i;
                    ct[rr * 264 + j] = f2bu(acc[mt][jt][i] + bias);
                }
        }
        __syncthreads();
        // phase 2: coalesced row stores (256B contiguous per 16 lanes)
        #pragma unroll
        for (int u = tid; u < PR * 32; u += 256) {     // uint4 units, 32/row
            int rr = u >> 5, i = u & 31;
            long row = n0 + rr;
            if (row < N_NODES) {
                uint4 v = *(const uint4*)&ct[rr * 264 + i * 8];
                if (i < 16) ((uint4*)(g  + row * EE))[i]      = v;
                else        ((uint4*)(h2 + row * EE))[i - 16] = v;
            }
        }
    } else {
        // ---- dist_mlp role: d(x) = sum_e W2[e]*relu(W1[e]*x+b1[e]) + b2 ----
        float4* w4 = (float4*)shb;                     // 2KB alias
        if (tid < EE) w4[tid] = make_float4(W1[tid], b1[tid], W2[tid], 0.f);
        __syncthreads();
        float b2s = b2v[0];
        int i0 = ((bx - GEMM_BLOCKS) * 256 + tid) * 4;
        float x[4], acc[4];
        #pragma unroll
        for (int j = 0; j < 4; ++j) {
            int i = i0 + j;
            x[j] = (i < NK) ? dists[i] : 0.f;
            acc[j] = b2s;
        }
        for (int e = 0; e < EE; ++e) {
            float4 w = w4[e];
            #pragma unroll
            for (int j = 0; j < 4; ++j)
                acc[j] += w.z * fmaxf(w.x * x[j] + w.y, 0.f);
        }
        #pragma unroll
        for (int j = 0; j < 4; ++j) {
            int i = i0 + j;
            if (i < NK) dstd[i] = acc[j];
        }
    }
}

// ---------------------------------------------------------------------------
// Fused gather + relu + Wp-dot + mean (exact R11 form — proven 51.5us).
// Wave-uniform n -> argmax row scalarizes (s_load), readfirstlane(row) ->
// SALU gather address + saddr global_load_dword. Packed f32 math
// (v_pk_fma/v_pk_add). Compiler schedules the gathers (R12's explicit ring
// regressed). grid N/4, block 256.
// ---------------------------------------------------------------------------
__global__ __launch_bounds__(256) void fused_msg(const int* __restrict__ argmax,
                                                 const u32* __restrict__ g,
                                                 const u32* __restrict__ h2,
                                                 const float* __restrict__ Wp,
                                                 const float* __restrict__ bpv,
                                                 float* outpos,
                                                 u32* __restrict__ meanws) {
    __shared__ u32 tile[WAVES][KK / 2][65];
    int tid = threadIdx.x;
    int lane = tid & 63;
    int wave = __builtin_amdgcn_readfirstlane(tid >> 6);
    int n = blockIdx.x * WAVES + wave;                 // wave-uniform

    const int* arow = argmax + (long)n * KK;           // uniform -> SMEM loads
    const float* drow = outpos + (long)n * KK;         // uniform base -> saddr

    u32 hu = h2[(long)n * (EE / 2) + lane];
    f32x2 hv; hv[0] = bflo(hu); hv[1] = bfhi(hu);
    float2 wpv = ((const float2*)Wp)[lane];
    float bpf = bpv[0];

    f32x2 am = {0.f, 0.f};
    const f32x2 zero2 = {0.f, 0.f};
    float ppe = 0.f;
    #pragma unroll
    for (int k = 0; k < KK; ++k) {
        int row = __builtin_amdgcn_readfirstlane(arow[k]);  // scalar row
        float dk = drow[k];                                  // lane-uniform
        const u32* gp = g + (long)row * (EE / 2);            // SALU address
        u32 gu = gp[lane];                                   // saddr + v_lane4
        f32x2 gv; gv[0] = bflo(gu); gv[1] = bfhi(gu);
        f32x2 dk2 = {dk, dk};
        f32x2 m = __builtin_elementwise_max(
                      __builtin_elementwise_fma(dk2, gv, hv), zero2);
        am += m;                                             // v_pk_add_f32
        float p = fmaf(m[1], wpv.y, m[0] * wpv.x);
        if (k & 1) tile[wave][k >> 1][lane] = packbf2(ppe, p);
        else       ppe = p;
    }
    meanws[(long)n * (EE / 2) + lane] = packbf2(am[0] * (1.f / KK), am[1] * (1.f / KK));

    int d = lane & 15;
    int j0 = (lane >> 4) * 16;
    f32x2 s = {0.f, 0.f};
    #pragma unroll
    for (int i = 0; i < 16; ++i) {
        u32 v = tile[wave][d][j0 + i];
        f32x2 pv; pv[0] = bflo(v); pv[1] = bfhi(v);
        s += pv;                                             // v_pk_add_f32
    }
    float s0 = s[0], s1 = s[1];
    s0 += __shfl_xor(s0, 16);
    s1 += __shfl_xor(s1, 16);
    s0 += __shfl_xor(s0, 32);
    s1 += __shfl_xor(s1, 32);
    if (lane < 16) {
        float2 o = make_float2(s0 + bpf, s1 + bpf);
        *(float2*)&outpos[(long)n * KK + 2 * d] = o;
    }
}

// ---------------------------------------------------------------------------
// MFMA GEMM: out_structure = [mean | ea] @ Ws^T + bs -> f32, overwrites the
// out_structure region. Block: 32 rows x 128 cols, K=256 (8 k-steps),
// 4 waves x (2 m-tiles x 2 j-tiles). A staged bf16 in LDS, stride 132 u32.
// grid ceil(N/32), block 256.
// ---------------------------------------------------------------------------
__global__ __launch_bounds__(256) void out_struct_mfma(const u16* __restrict__ meanws,
                                                       const float* __restrict__ edge_attr,
                                                       const u16* __restrict__ Wstp,
                                                       const float* __restrict__ bs,
                                                       float* __restrict__ outs) {
    __shared__ u32 at[PR * 132];
    int tid = threadIdx.x;
    int n0 = blockIdx.x * PR;
    for (int idx = tid; idx < PR * 64; idx += 256) {   // mean: u32 units, 64/row
        int rr = idx >> 6, c = idx & 63;
        long row = n0 + rr; if (row >= N_NODES) row = N_NODES - 1;
        at[rr * 132 + c] = ((const u32*)meanws)[row * 64 + c];
    }
    for (int idx = tid; idx < PR * 32; idx += 256) {   // ea: float4 units, 32/row
        int rr = idx >> 5, c4 = idx & 31;
        long row = n0 + rr; if (row >= N_NODES) row = N_NODES - 1;
        float4 v = ((const float4*)(edge_attr + row * EE))[c4];
        at[rr * 132 + 64 + 2 * c4]     = packbf2(v.x, v.y);
        at[rr * 132 + 64 + 2 * c4 + 1] = packbf2(v.z, v.w);
    }
    __syncthreads();
    int lane = tid & 63, wave = tid >> 6;
    int col = lane & 15, quad = lane >> 4;
    f32x4 acc[2][2] = {};
    #pragma unroll
    for (int t = 0; t < 8; ++t) {
        bf16x8 a0 = *(const bf16x8*)&at[col * 132 + t * 16 + quad * 4];
        bf16x8 a1 = *(const bf16x8*)&at[(16 + col) * 132 + t * 16 + quad * 4];
        #pragma unroll
        for (int jt = 0; jt < 2; ++jt) {
            int jtg = wave * 2 + jt;
            bf16x8 b = *(const bf16x8*)&Wstp[((long)(t * 8 + jtg) * 64 + lane) * 8];
            acc[0][jt] = __builtin_amdgcn_mfma_f32_16x16x32_bf16(a0, b, acc[0][jt], 0, 0, 0);
            acc[1][jt] = __builtin_amdgcn_mfma_f32_16x16x32_bf16(a1, b, acc[1][jt], 0, 0, 0);
        }
    }
    #pragma unroll
    for (int jt = 0; jt < 2; ++jt) {
        int j = wave * 32 + jt * 16 + col;             // 0..127
        float bias = bs[j];
        #pragma unroll
        for (int mt = 0; mt < 2; ++mt)
            #pragma unroll
            for (int i = 0; i < 4; ++i) {
                long row = n0 + mt * 16 + quad * 4 + i;
                if (row < N_NODES) outs[row * EE + j] = acc[mt][jt][i] + bias;
            }
    }
}

extern "C" void kernel_launch(void* const* d_in, const int* in_sizes, int n_in,
                              void* d_out, int out_size, void* d_ws, size_t ws_size,
                              hipStream_t stream) {
    const float* feature   = (const float*)d_in[0];
    const float* dists_max = (const float*)d_in[1];
    const int* dists_argmax = (const int*)d_in[2];
    const float* edge_attr = (const float*)d_in[3];
    const float* W1 = (const float*)d_in[4];
    const float* b1 = (const float*)d_in[5];
    const float* W2 = (const float*)d_in[6];
    const float* b2 = (const float*)d_in[7];
    const float* Wf = (const float*)d_in[8];
    const float* bf = (const float*)d_in[9];
    const float* Wh = (const float*)d_in[10];
    const float* bh = (const float*)d_in[11];
    const float* Wp = (const float*)d_in[12];
    const float* bp = (const float*)d_in[13];
    const float* Ws = (const float*)d_in[14];
    const float* bs = (const float*)d_in[15];

    float* outpos = (float*)d_out;        // [N,K] f32: d scratch, then pos
    float* outs   = outpos + NK;          // [N,E] f32: g+h2 bf16 scratch, then out_structure
    u16* g  = (u16*)outs;                 // [N,E] bf16  (12.8 MB)
    u16* h2 = g + NE;                     // [N,E] bf16  (12.8 MB)

    // Workspace (same footprint as R5-R12): 0.26 MB f32 + 12.8 MB bf16.
    float* Acm  = (float*)d_ws;           // [EE*EE]  (unused, layout anchor)
    float* Bcm  = Acm + EE * EE;          // [EE*EE]  (unused)
    float* agf  = Bcm + EE * EE;          // [EE]
    float* bh2f = agf + EE;               // [EE]
    float* Wst  = bh2f + EE;              // [2*EE*EE] area, reused for packs:
    u16* Wghp = (u16*)Wst;                //   64 KB (4*16 frag-tiles)
    u16* Wstp = Wghp + 64 * 512;          //   64 KB (8*8 frag-tiles)
    u16* meanws = (u16*)(Wst + 2 * EE * EE);  // [N*E] bf16 (unchanged offset)

    prep_pack<<<320, 128, 0, stream>>>(Wh, Wf, bf, bh, Ws, Wghp, Wstp, agf, bh2f);
    proj_dist<<<GEMM_BLOCKS + DIST_BLOCKS, 256, 0, stream>>>(
        feature, Wghp, agf, bh2f, g, h2,
        dists_max, W1, b1, W2, b2, outpos);
    fused_msg<<<N_NODES / WAVES, 256, 0, stream>>>(dists_argmax, (const u32*)g,
                                                   (const u32*)h2, Wp, bp,
                                                   outpos, (u32*)meanws);
    out_struct_mfma<<<GEMM_BLOCKS, 256, 0, stream>>>(meanws, edge_attr, Wstp, bs, outs);
}